// Round 12
// baseline (288.387 us; speedup 1.0000x reference)
//
#include <hip/hip_runtime.h>

// VectorQuantizer on MI355X — round 12: screen v5 — B read directly from L2
// (no B-LDS, no dbuf, no per-phase barriers; 4 blocks/CU).
// z: (64,256,32,32) f32; emb: (1024,256) f32.
// out (f32): [0,16777216) z_q_out | [16777216] loss | [16777217,+65536) indices
//
// ws layout (bytes):
//   0        double   loss_acc                 (memset 0)
//   64       int      widx[65536]
//   262208   float    e2[1024]                 (numpy-pairwise fp32)
//   266304   float    z2[65536]                (numpy-pairwise fp32)
//   528448   int      gcnt[65536]
//   790592   ushort   gcand[65536*16]
//   2887744  _Float16 Ef[1024*256]             (f16 RNE copy of emb)

typedef _Float16 f16x8 __attribute__((ext_vector_type(8)));
typedef float f32x4 __attribute__((ext_vector_type(4)));

#define VQ_W 1.5e-3f
#define SCR_LDS_BYTES 35328
#define RES_LDS_BYTES (65792 + 512)
#define OUT_LDS_BYTES 66560

// fl32(v*v) with a barrier so the product cannot be contracted into a later add.
__device__ __forceinline__ float sq_rnd(float v) {
  float y = v * v;
  asm volatile("" : "+v"(y));
  return y;
}

// numpy pairwise_sum over 256 fp32 squared terms (8-accumulator blocks of 128).
__device__ float np_pw256_sq(const float* base, int stride) {
  float tot0, tot1;
  {
    const float* a = base;
    float r[8];
    #pragma unroll
    for (int j = 0; j < 8; ++j) r[j] = sq_rnd(a[j * stride]);
    #pragma unroll 1
    for (int i = 8; i < 128; i += 8) {
      #pragma unroll
      for (int j = 0; j < 8; ++j) r[j] += sq_rnd(a[(i + j) * stride]);
    }
    tot0 = ((r[0] + r[1]) + (r[2] + r[3])) + ((r[4] + r[5]) + (r[6] + r[7]));
  }
  {
    const float* a = base + 128 * stride;
    float r[8];
    #pragma unroll
    for (int j = 0; j < 8; ++j) r[j] = sq_rnd(a[j * stride]);
    #pragma unroll 1
    for (int i = 8; i < 128; i += 8) {
      #pragma unroll
      for (int j = 0; j < 8; ++j) r[j] += sq_rnd(a[(i + j) * stride]);
    }
    tot1 = ((r[0] + r[1]) + (r[2] + r[3])) + ((r[4] + r[5]) + (r[6] + r[7]));
  }
  return tot0 + tot1;
}

__global__ __launch_bounds__(256) void vq_prep(const float* __restrict__ emb,
                                               _Float16* __restrict__ Ef,
                                               float* __restrict__ e2) {
  const int g = blockIdx.x * 256 + threadIdx.x;  // 0..262143
  Ef[g] = (_Float16)emb[g];                      // RNE v_cvt_f16_f32
  if (g < 1024) e2[g] = np_pw256_sq(emb + g * 256, 1);
}

// |z|^2 per point, numpy-pairwise, v3 (r11-verified): 16 threads/point (one per
// accumulator chain), 16 points/block, 4096 blocks; exact np combine trees.
__global__ __launch_bounds__(256) void vq_z2(const float* __restrict__ z,
                                             float* __restrict__ z2) {
  __shared__ float sm[256];  // [chain c][point p] = sm[c*16+p]
  const int tid = threadIdx.x;
  const int p = tid & 15;
  const int c = tid >> 4;
  const int n0 = blockIdx.x * 16;
  const int n = n0 + p;
  const int bb = n >> 10, hw = n & 1023;
  const float* zp = z + bb * 262144 + hw;
  const int dbase = (c >> 3) * 128 + (c & 7);
  float r = sq_rnd(zp[dbase * 1024]);
  #pragma unroll
  for (int i = 1; i < 16; ++i) r += sq_rnd(zp[(dbase + 8 * i) * 1024]);
  sm[c * 16 + p] = r;
  __syncthreads();
  if (tid < 16) {
    const int pp = tid;
    float h0[8], h1[8];
    #pragma unroll
    for (int j = 0; j < 8; ++j) {
      h0[j] = sm[j * 16 + pp];
      h1[j] = sm[(8 + j) * 16 + pp];
    }
    const float tot0 = ((h0[0] + h0[1]) + (h0[2] + h0[3])) +
                       ((h0[4] + h0[5]) + (h0[6] + h0[7]));
    const float tot1 = ((h1[0] + h1[1]) + (h1[2] + h1[3])) +
                       ((h1[4] + h1[5]) + (h1[6] + h1[7]));
    z2[n0 + pp] = tot0 + tot1;
  }
}

// Screening v5: f16 MFMA, block = 64 points x 1024 codes. A (z) resident in LDS
// (32KB, XOR-swizzled rows, r5-verified). B fragments read DIRECTLY from Ef in
// L2 (512KB, resident): lane reads 16B at Ef[code*256 + ph*32 + q*8] — byte-
// identical to the old staged path (store slot s<-octet s^(r&3), read q^(l&3),
// l&3==ln&3 -> octet q). (ln,q) lanes form full 64B lines -> coalesced L2.
// No per-phase barriers (A read-only); 1 barrier per chunk epilogue (prefix-min
// superset logic, r9-verified; wave-skew safe: runminU monotone decreasing).
__global__ __launch_bounds__(256, 4) void vq_screen(
    const float* __restrict__ z, const _Float16* __restrict__ Ef,
    const float* __restrict__ e2, const float* __restrict__ z2,
    int* __restrict__ gcnt, unsigned short* __restrict__ gcand) {
  extern __shared__ __align__(16) char smem[];
  // [0,32768) A; 32768 runminU[64]; 33024 cnt[64]; 33280 cand[64][16]
  unsigned* runminU = (unsigned*)(smem + 32768);
  int* cnt = (int*)(smem + 33024);
  unsigned short* cand = (unsigned short*)(smem + 33280);

  const int tid = threadIdx.x;
  const int blk = blockIdx.x;
  const int n0 = blk * 64;
  const int bb = blk >> 4;
  const int hw0 = (blk & 15) * 64;
  const float* zb = z + bb * 262144 + hw0;

  if (tid < 64) { runminU[tid] = 0x7F800000u; cnt[tid] = 0; }

  {  // A stage: convert z tile to f16, swizzled rows
    const int p = tid & 63, dh = tid >> 6;
    #pragma unroll
    for (int dq = 0; dq < 8; ++dq) {
      const int d0 = dh * 64 + dq * 8;
      f16x8 hv;
      #pragma unroll
      for (int j = 0; j < 8; ++j) hv[j] = (_Float16)zb[(d0 + j) * 1024 + p];
      *(f16x8*)&smem[p * 512 + ((d0 * 2) ^ ((p & 7) * 16))] = hv;
    }
  }

  const int l = tid & 63;
  const int ln = l & 15;
  const int q = l >> 4;
  const int wc = tid >> 6;        // wave: codes wc*64 .. +63 per chunk
  const int xr = (l & 7) * 16;

  float z2r[4][4];
  #pragma unroll
  for (int fi = 0; fi < 4; ++fi)
    #pragma unroll
    for (int rg = 0; rg < 4; ++rg)
      z2r[fi][rg] = z2[n0 + fi * 16 + q * 4 + rg];

  f32x4 acc[4][4];
  #pragma unroll
  for (int fi = 0; fi < 4; ++fi)
    #pragma unroll
    for (int fj = 0; fj < 4; ++fj) acc[fi][fj] = (f32x4){0.f, 0.f, 0.f, 0.f};

  __syncthreads();

  for (int p = 0; p < 32; ++p) {
    const int ph = p & 7;
    const int cc = p >> 3;
    {  // compute phase p: B direct from L2, A from LDS
      const _Float16* Eb =
          Ef + (cc * 256 + wc * 64 + ln) * 256 + ph * 32 + q * 8;
      f16x8 aF[4], bF[4];
      #pragma unroll
      for (int fj = 0; fj < 4; ++fj)
        bF[fj] = *(const f16x8*)(Eb + fj * 16 * 256);
      const int ab = (ph * 64 + q * 16) ^ xr;
      #pragma unroll
      for (int fi = 0; fi < 4; ++fi)
        aF[fi] = *(const f16x8*)&smem[(fi * 16 + ln) * 512 + ab];
      #pragma unroll
      for (int fi = 0; fi < 4; ++fi)
        #pragma unroll
        for (int fj = 0; fj < 4; ++fj)
          acc[fi][fj] = __builtin_amdgcn_mfma_f32_16x16x32_f16(
              aF[fi], bF[fj], acc[fi][fj], 0, 0, 0);
    }
    if (ph == 7) {  // chunk epilogue: exact prefix-min via one barrier
      const int cbase = cc * 256 + wc * 64 + ln;
      float e2v[4];
      #pragma unroll
      for (int fj = 0; fj < 4; ++fj) e2v[fj] = e2[cbase + fj * 16];
      // Phase 1: wave-local mins -> atomicMin into runminU
      #pragma unroll
      for (int fi = 0; fi < 4; ++fi) {
        #pragma unroll
        for (int rg = 0; rg < 4; ++rg) {
          float rm = 3.4e38f;
          #pragma unroll
          for (int fj = 0; fj < 4; ++fj)
            rm = fminf(rm, fmaf(-2.f, acc[fi][fj][rg], z2r[fi][rg] + e2v[fj]));
          rm = fminf(rm, __shfl_xor(rm, 1));
          rm = fminf(rm, __shfl_xor(rm, 2));
          rm = fminf(rm, __shfl_xor(rm, 4));
          rm = fminf(rm, __shfl_xor(rm, 8));
          if (ln == 0)
            atomicMin(&runminU[fi * 16 + q * 4 + rg], __float_as_uint(rm));
        }
      }
      __syncthreads();  // runminU now = true min over ALL codes up to chunk cc
      // Phase 2: collect candidates against the exact prefix min
      #pragma unroll
      for (int fi = 0; fi < 4; ++fi) {
        #pragma unroll
        for (int rg = 0; rg < 4; ++rg) {
          const int row = fi * 16 + q * 4 + rg;
          const float thr = __uint_as_float(runminU[row]) + VQ_W;
          #pragma unroll
          for (int fj = 0; fj < 4; ++fj) {
            const float sv = fmaf(-2.f, acc[fi][fj][rg], z2r[fi][rg] + e2v[fj]);
            if (sv <= thr) {
              const int slot = atomicAdd(&cnt[row], 1);
              if (slot < 16)
                cand[row * 16 + slot] = (unsigned short)(cbase + fj * 16);
            }
          }
        }
        #pragma unroll
        for (int fj = 0; fj < 4; ++fj) acc[fi][fj] = (f32x4){0.f, 0.f, 0.f, 0.f};
      }
    }
  }

  __syncthreads();
  if (tid < 64) gcnt[n0 + tid] = cnt[tid];
  {
    const int rr = tid >> 2, si = (tid & 3) * 4;
    *(uint2*)&gcand[(n0 + rr) * 16 + si] = *(const uint2*)&cand[rr * 16 + si];
  }
}

// Rescore (r6-verified): block = 64 points, z-tile in LDS, 4 threads/point split
// candidates; merge via LDS u64 atomicMin on (score_bits<<10)|k. Writes indices
// output directly.
__global__ __launch_bounds__(256) void vq_rescore(
    const float* __restrict__ z, const float* __restrict__ emb,
    const float* __restrict__ e2, const float* __restrict__ z2,
    const int* __restrict__ gcnt, const unsigned short* __restrict__ gcand,
    int* __restrict__ widx, float* __restrict__ out) {
  extern __shared__ __align__(16) char rsmem[];
  float* zt = (float*)rsmem;                                        // [64][257]
  unsigned long long* best = (unsigned long long*)(rsmem + 65792);  // [64]

  const int tid = threadIdx.x;
  const int w = tid >> 6;
  const int l = tid & 63;
  const int n0 = blockIdx.x << 6;
  const int bb = n0 >> 10, hw0 = n0 & 1023;
  const int n = n0 + l;

  const int c = gcnt[n];
  if (!__any(c >= 2)) {  // block-uniform: all waves see identical l-range
    if (w == 0) {
      const int v = gcand[n * 16];
      widx[n] = v;
      out[16777217 + n] = (float)v;
    }
    return;
  }

  {  // stage z tile
    const float* zb = z + bb * 262144 + hw0;
    #pragma unroll 8
    for (int it = 0; it < 64; ++it) {
      const int d = it * 4 + w;
      zt[l * 257 + d] = zb[d * 1024 + l];
    }
  }
  if (tid < 64) best[tid] = ~0ULL;
  __syncthreads();

  if (c >= 2) {
    const float z2n = z2[n];
    const float* zrow = &zt[l * 257];
    if (c <= 16) {
      for (int s = w; s < c; s += 4) {
        const int k = gcand[n * 16 + s];
        const float* ep = emb + k * 256;
        float a = 0.f;
        #pragma unroll 4
        for (int d = 0; d < 256; ++d) a = fmaf(zrow[d], ep[d], a);
        const float sv = fmaf(-2.f, a, z2n + e2[k]);
        const unsigned long long key =
            ((unsigned long long)__float_as_uint(sv) << 10) | (unsigned)k;
        atomicMin(&best[l], key);
      }
    } else {  // overflow fallback: exact full scan
      for (int k = w; k < 1024; k += 4) {
        const float* ep = emb + k * 256;
        float a = 0.f;
        #pragma unroll 4
        for (int d = 0; d < 256; ++d) a = fmaf(zrow[d], ep[d], a);
        const float sv = fmaf(-2.f, a, z2n + e2[k]);
        const unsigned long long key =
            ((unsigned long long)__float_as_uint(sv) << 10) | (unsigned)k;
        atomicMin(&best[l], key);
      }
    }
  }
  __syncthreads();
  if (tid < 64) {
    const int cc = gcnt[n0 + tid];
    const int v = (cc == 1) ? (int)gcand[(n0 + tid) * 16]
                            : (int)(best[tid] & 1023ULL);
    widx[n0 + tid] = v;
    out[16777217 + n0 + tid] = (float)v;
  }
}

// Output + loss (r3-verified). Gather 64 emb rows into LDS row-coalesced, then
// transpose-read (stride 260) + coalesced global write.
__global__ __launch_bounds__(256) void vq_out(const float* __restrict__ z,
                                              const float* __restrict__ emb,
                                              const int* __restrict__ widx,
                                              float* __restrict__ out,
                                              double* __restrict__ acc) {
  extern __shared__ float rows[];  // [64][260]
  const int tid = threadIdx.x;
  const int w = tid >> 6, l = tid & 63;
  const int n0 = blockIdx.x << 6;
  const int bb = n0 >> 10, hw0 = n0 & 1023;

  #pragma unroll 4
  for (int rr = 0; rr < 16; ++rr) {
    const int r = rr * 4 + w;
    const int idx = widx[n0 + r];
    const float4 ev = *(const float4*)&emb[idx * 256 + l * 4];
    *(float4*)&rows[r * 260 + l * 4] = ev;
  }
  __syncthreads();

  const int zofs = bb * 262144 + hw0 + l;
  const float* zp = z + zofs;
  float* op = out + zofs;
  double ls = 0.0;
  #pragma unroll 2
  for (int i16 = 0; i16 < 16; ++i16) {
    const int d4 = w * 64 + i16 * 4;
    const float4 q4 = *(const float4*)&rows[l * 260 + d4];
    #pragma unroll
    for (int e = 0; e < 4; ++e) {
      const int d = d4 + e;
      const float zv = zp[d * 1024];
      const float qv = ((const float*)&q4)[e];
      float df = qv - zv;
      asm volatile("" : "+v"(df));
      op[d * 1024] = zv + df;  // fl(z + fl(z_q - z))
      ls += (double)df * df;
    }
  }
  #pragma unroll
  for (int off = 32; off > 0; off >>= 1) ls += __shfl_down(ls, off);
  if (l == 0) atomicAdd(acc, ls);
}

__global__ void vq_fin(const double* __restrict__ acc, float* __restrict__ out) {
  if (threadIdx.x == 0)
    out[16777216] = (float)(1.25 * (*acc) * (1.0 / 16777216.0));
}

extern "C" void kernel_launch(void* const* d_in, const int* in_sizes, int n_in,
                              void* d_out, int out_size, void* d_ws, size_t ws_size,
                              hipStream_t stream) {
  const float* z = (const float*)d_in[0];
  const float* emb = (const float*)d_in[1];
  float* out = (float*)d_out;
  char* ws = (char*)d_ws;
  double* acc = (double*)(ws);
  int* widx = (int*)(ws + 64);
  float* e2 = (float*)(ws + 262208);
  float* z2 = (float*)(ws + 266304);
  int* gcnt = (int*)(ws + 528448);
  unsigned short* gcand = (unsigned short*)(ws + 790592);
  _Float16* Ef = (_Float16*)(ws + 2887744);

  hipFuncSetAttribute(reinterpret_cast<const void*>(vq_screen),
                      hipFuncAttributeMaxDynamicSharedMemorySize, SCR_LDS_BYTES);
  hipFuncSetAttribute(reinterpret_cast<const void*>(vq_rescore),
                      hipFuncAttributeMaxDynamicSharedMemorySize, RES_LDS_BYTES);
  hipFuncSetAttribute(reinterpret_cast<const void*>(vq_out),
                      hipFuncAttributeMaxDynamicSharedMemorySize, OUT_LDS_BYTES);

  hipMemsetAsync(ws, 0, 64, stream);
  vq_prep<<<1024, 256, 0, stream>>>(emb, Ef, e2);
  vq_z2<<<4096, 256, 0, stream>>>(z, z2);
  vq_screen<<<1024, 256, SCR_LDS_BYTES, stream>>>(z, Ef, e2, z2, gcnt, gcand);
  vq_rescore<<<1024, 256, RES_LDS_BYTES, stream>>>(z, emb, e2, z2, gcnt, gcand,
                                                   widx, out);
  vq_out<<<1024, 256, OUT_LDS_BYTES, stream>>>(z, emb, widx, out, acc);
  vq_fin<<<1, 64, 0, stream>>>(acc, out);
}